// Round 1
// baseline (207.761 us; speedup 1.0000x reference)
//
#include <hip/hip_runtime.h>

// 1024-point FFT of real input, batched. Radix-4 Stockham DIF, 5 stages.
// One block of 256 threads per row; each thread does one radix-4 butterfly
// per stage. Stage 0 fused with global load (imag=0), stage 4 fused with
// global store (Stockham output is natural order). Exact twiddles from
// input tw_real_3/tw_imag_3 (= w_1024^k, k<512), extended by negation.

#define N_FFT 1024
#define BATCH 16384
#define TPB   256

// LDS pad: +1 float2 per 16 -> spreads strided write patterns evenly over banks
__device__ __forceinline__ int pad16(int a) { return a + (a >> 4); }

__device__ __forceinline__ float2 cmul(float2 a, float2 b) {
    return make_float2(a.x * b.x - a.y * b.y, a.x * b.y + a.y * b.x);
}

template<int M, int STEP>
__device__ __forceinline__ void stage_mid(const float2* __restrict__ src,
                                          float2* __restrict__ dst,
                                          const float2* __restrict__ tw,
                                          int tid)
{
    const int j = tid / M;
    const int k = tid % M;
    float2 a = src[pad16(tid)];
    float2 b = src[pad16(tid + 256)];
    float2 c = src[pad16(tid + 512)];
    float2 d = src[pad16(tid + 768)];
    float2 t0 = make_float2(a.x + c.x, a.y + c.y);
    float2 t1 = make_float2(a.x - c.x, a.y - c.y);
    float2 t2 = make_float2(b.x + d.x, b.y + d.y);
    float2 t3 = make_float2(b.y - d.y, d.x - b.x);   // -i*(b-d)
    float2 y0 = make_float2(t0.x + t2.x, t0.y + t2.y);
    float2 u1 = make_float2(t1.x + t3.x, t1.y + t3.y);
    float2 u2 = make_float2(t0.x - t2.x, t0.y - t2.y);
    float2 u3 = make_float2(t1.x - t3.x, t1.y - t3.y);
    float2 w1 = tw[STEP * j];
    float2 w2 = tw[2 * STEP * j];
    float2 w3 = tw[3 * STEP * j];
    const int base = 4 * M * j + k;
    dst[pad16(base)]         = y0;
    dst[pad16(base + M)]     = cmul(u1, w1);
    dst[pad16(base + 2 * M)] = cmul(u2, w2);
    dst[pad16(base + 3 * M)] = cmul(u3, w3);
}

__global__ __launch_bounds__(TPB) void fft1024_kernel(
    const float* __restrict__ x,
    const float* __restrict__ twr,   // tw_real_3: w_1024^k re, k<512
    const float* __restrict__ twi,   // tw_imag_3: w_1024^k im, k<512
    float* __restrict__ outr,
    float* __restrict__ outi)
{
    __shared__ float2 bufA[1088];   // 1024 + 1024/16 pad
    __shared__ float2 bufB[1088];
    __shared__ float2 tw[1024];

    const int tid = threadIdx.x;
    const long long row = blockIdx.x;

    // Build full w_1024^k table, k=0..1023 (w^{k+512} = -w^k)
    for (int i = tid; i < 512; i += TPB) {
        float r = twr[i], im = twi[i];
        tw[i]       = make_float2(r, im);
        tw[i + 512] = make_float2(-r, -im);
    }
    __syncthreads();

    const float* __restrict__ xr = x + row * N_FFT;

    // ---- stage 0: m=1, l=256, real input from global ----
    {
        float a = xr[tid];
        float b = xr[tid + 256];
        float c = xr[tid + 512];
        float d = xr[tid + 768];
        float t0 = a + c, t1 = a - c;
        float t2 = b + d, t3 = d - b;   // imag part of -i*(b-d)
        float2 w1 = tw[tid];
        float2 w2 = tw[2 * tid];
        float2 w3 = tw[3 * tid];
        const int base = 4 * tid;
        bufA[pad16(base)]     = make_float2(t0 + t2, 0.0f);
        bufA[pad16(base + 1)] = make_float2(t1 * w1.x - t3 * w1.y,
                                            t1 * w1.y + t3 * w1.x);
        bufA[pad16(base + 2)] = make_float2((t0 - t2) * w2.x,
                                            (t0 - t2) * w2.y);
        bufA[pad16(base + 3)] = make_float2(t1 * w3.x + t3 * w3.y,
                                            t1 * w3.y - t3 * w3.x);
    }
    __syncthreads();

    stage_mid<4, 4>(bufA, bufB, tw, tid);    // stage 1: m=4,  l=64
    __syncthreads();
    stage_mid<16, 16>(bufB, bufA, tw, tid);  // stage 2: m=16, l=16
    __syncthreads();
    stage_mid<64, 64>(bufA, bufB, tw, tid);  // stage 3: m=64, l=4
    __syncthreads();

    // ---- stage 4: m=256, l=1, j=0 (unit twiddles), natural-order store ----
    {
        float2 a = bufB[pad16(tid)];
        float2 b = bufB[pad16(tid + 256)];
        float2 c = bufB[pad16(tid + 512)];
        float2 d = bufB[pad16(tid + 768)];
        float2 t0 = make_float2(a.x + c.x, a.y + c.y);
        float2 t1 = make_float2(a.x - c.x, a.y - c.y);
        float2 t2 = make_float2(b.x + d.x, b.y + d.y);
        float2 t3 = make_float2(b.y - d.y, d.x - b.x);
        float* __restrict__ orow = outr + row * N_FFT;
        float* __restrict__ irow = outi + row * N_FFT;
        orow[tid]       = t0.x + t2.x;  irow[tid]       = t0.y + t2.y;
        orow[tid + 256] = t1.x + t3.x;  irow[tid + 256] = t1.y + t3.y;
        orow[tid + 512] = t0.x - t2.x;  irow[tid + 512] = t0.y - t2.y;
        orow[tid + 768] = t1.x - t3.x;  irow[tid + 768] = t1.y - t3.y;
    }
}

extern "C" void kernel_launch(void* const* d_in, const int* in_sizes, int n_in,
                              void* d_out, int out_size, void* d_ws, size_t ws_size,
                              hipStream_t stream) {
    // setup_inputs order:
    // 0:x 1:perm 2:fft_real 3:fft_imag 4..11: tw_{real,imag}_{0..3}
    const float* x   = (const float*)d_in[0];
    const float* twr = (const float*)d_in[10];  // 512 entries: w_1024^k real
    const float* twi = (const float*)d_in[11];  // 512 entries: w_1024^k imag
    float* outr = (float*)d_out;
    float* outi = outr + (size_t)BATCH * N_FFT;
    fft1024_kernel<<<BATCH, TPB, 0, stream>>>(x, twr, twi, outr, outi);
}

// Round 2
// 206.091 us; speedup vs baseline: 1.0081x; 1.0081x over previous
//
#include <hip/hip_runtime.h>

// 1024-point FFT of real input, batched 16384. Two-for-one packing:
// each block handles TWO rows as one complex sequence z = x0 + i*x1,
// runs a radix-4 Stockham DIF FFT (5 stages, 256 threads, one butterfly
// per thread per stage), then unpacks both spectra via conjugate symmetry
// and stores natural-order coalesced.
//
// Exact twiddles from input tw_real_3/tw_imag_3 (= w_1024^k, k<512),
// extended to k<1024 by negation.

#define N_FFT 1024
#define BATCH 16384
#define TPB   256

// LDS pad: +1 float2 per 16 slots -> strided write patterns spread over banks
__device__ __forceinline__ int pad16(int a) { return a + (a >> 4); }

__device__ __forceinline__ float2 cmul(float2 a, float2 b) {
    return make_float2(a.x * b.x - a.y * b.y, a.x * b.y + a.y * b.x);
}

// One radix-4 DIF butterfly + twiddle + strided store to LDS.
// Thread tid owns (j = tid/M, k = tid%M); inputs are x[tid + q*256].
template<int M, int STEP>
__device__ __forceinline__ void butterfly_store(float2 a, float2 b, float2 c, float2 d,
                                                float2* __restrict__ dst,
                                                const float2* __restrict__ tw,
                                                int tid)
{
    const int j = tid / M;
    const int k = tid % M;
    float2 t0 = make_float2(a.x + c.x, a.y + c.y);
    float2 t1 = make_float2(a.x - c.x, a.y - c.y);
    float2 t2 = make_float2(b.x + d.x, b.y + d.y);
    float2 t3 = make_float2(b.y - d.y, d.x - b.x);   // -i*(b-d)
    float2 y0 = make_float2(t0.x + t2.x, t0.y + t2.y);
    float2 u1 = make_float2(t1.x + t3.x, t1.y + t3.y);
    float2 u2 = make_float2(t0.x - t2.x, t0.y - t2.y);
    float2 u3 = make_float2(t1.x - t3.x, t1.y - t3.y);
    float2 w1 = tw[STEP * j];
    float2 w2 = tw[2 * STEP * j];
    float2 w3 = tw[3 * STEP * j];
    const int base = 4 * M * j + k;
    dst[pad16(base)]         = y0;
    dst[pad16(base + M)]     = cmul(u1, w1);
    dst[pad16(base + 2 * M)] = cmul(u2, w2);
    dst[pad16(base + 3 * M)] = cmul(u3, w3);
}

template<int M, int STEP>
__device__ __forceinline__ void stage_mid(const float2* __restrict__ src,
                                          float2* __restrict__ dst,
                                          const float2* __restrict__ tw,
                                          int tid)
{
    float2 a = src[pad16(tid)];
    float2 b = src[pad16(tid + 256)];
    float2 c = src[pad16(tid + 512)];
    float2 d = src[pad16(tid + 768)];
    butterfly_store<M, STEP>(a, b, c, d, dst, tw, tid);
}

__global__ __launch_bounds__(TPB) void fft1024_kernel(
    const float* __restrict__ x,
    const float* __restrict__ twr,   // w_1024^k re, k<512
    const float* __restrict__ twi,   // w_1024^k im, k<512
    float* __restrict__ outr,
    float* __restrict__ outi)
{
    __shared__ float2 bufA[1088];   // 1024 + 64 pad slots
    __shared__ float2 bufB[1088];
    __shared__ float2 tw[1024];

    const int tid = threadIdx.x;
    const long long r0 = 2LL * blockIdx.x;      // even row
    // odd row = r0 + 1 (contiguous in memory)

    for (int i = tid; i < 512; i += TPB) {
        float re = twr[i], im = twi[i];
        tw[i]       = make_float2(re, im);
        tw[i + 512] = make_float2(-re, -im);
    }
    __syncthreads();

    const float* __restrict__ x0 = x + r0 * N_FFT;
    const float* __restrict__ x1 = x0 + N_FFT;

    // ---- stage 0: m=1, complex input z = x0 + i*x1, from global ----
    {
        float2 a = make_float2(x0[tid],       x1[tid]);
        float2 b = make_float2(x0[tid + 256], x1[tid + 256]);
        float2 c = make_float2(x0[tid + 512], x1[tid + 512]);
        float2 d = make_float2(x0[tid + 768], x1[tid + 768]);
        butterfly_store<1, 1>(a, b, c, d, bufA, tw, tid);
    }
    __syncthreads();

    stage_mid<4, 4>(bufA, bufB, tw, tid);     // stage 1
    __syncthreads();
    stage_mid<16, 16>(bufB, bufA, tw, tid);   // stage 2
    __syncthreads();
    stage_mid<64, 64>(bufA, bufB, tw, tid);   // stage 3
    __syncthreads();
    stage_mid<256, 0>(bufB, bufA, tw, tid);   // stage 4: j=0, unit twiddles
    __syncthreads();

    // ---- unpack two real-input spectra from Z and store ----
    float* __restrict__ or0 = outr + r0 * N_FFT;
    float* __restrict__ oi0 = outi + r0 * N_FFT;
    float* __restrict__ or1 = or0 + N_FFT;
    float* __restrict__ oi1 = oi0 + N_FFT;
    #pragma unroll
    for (int q = 0; q < 4; ++q) {
        const int k  = tid + q * 256;
        const int nk = (N_FFT - k) & (N_FFT - 1);
        float2 zk = bufA[pad16(k)];
        float2 zn = bufA[pad16(nk)];
        // X0 = (Z(k) + conj(Z(-k)))/2 ; X1 = -i*(Z(k) - conj(Z(-k)))/2
        or0[k] = 0.5f * (zk.x + zn.x);
        oi0[k] = 0.5f * (zk.y - zn.y);
        or1[k] = 0.5f * (zk.y + zn.y);
        oi1[k] = 0.5f * (zn.x - zk.x);
    }
}

extern "C" void kernel_launch(void* const* d_in, const int* in_sizes, int n_in,
                              void* d_out, int out_size, void* d_ws, size_t ws_size,
                              hipStream_t stream) {
    // setup_inputs order:
    // 0:x 1:perm 2:fft_real 3:fft_imag 4..11: tw_{real,imag}_{0..3}
    const float* x   = (const float*)d_in[0];
    const float* twr = (const float*)d_in[10];  // 512 entries: w_1024^k real
    const float* twi = (const float*)d_in[11];  // 512 entries: w_1024^k imag
    float* outr = (float*)d_out;
    float* outi = outr + (size_t)BATCH * N_FFT;
    fft1024_kernel<<<BATCH / 2, TPB, 0, stream>>>(x, twr, twi, outr, outi);
}